// Round 7
// baseline (1075.899 us; speedup 1.0000x reference)
//
#include <hip/hip_runtime.h>
#include <hip/hip_bf16.h>
#include <math.h>

#define POST 128
#define NI 129            // T+1
#define NJK 4225          // 65*65
#define KPAD 4288         // 67*64
#define NTOT 16512        // 129*128
#define KBLKS 134         // KPAD/32 (k-blocks of 32)
#define MBLKS 32          // 512/16
#define KSTEPS 67         // KPAD/64

typedef __attribute__((ext_vector_type(8))) short bf16x8;
typedef __attribute__((ext_vector_type(4))) float f32x4;
typedef __attribute__((ext_vector_type(4))) unsigned int u32x4;

__device__ __forceinline__ unsigned short f2bf(float f){
    unsigned u = __builtin_bit_cast(unsigned, f);
    unsigned r = (u + 0x7FFFu + ((u >> 16) & 1u)) >> 16;   // RNE
    return (unsigned short)r;
}
__device__ __forceinline__ unsigned pack2(float a, float b){
    return (unsigned)f2bf(a) | ((unsigned)f2bf(b) << 16);
}

// ---------------- K1: build VA (bf16) in MFMA A-fragment granule order --------
__global__ void build_af(const float* __restrict__ audio,
                         const float* __restrict__ video,
                         uint4* __restrict__ af)
{
    int gid = blockIdx.x * 256 + threadIdx.x;
    if (gid >= KBLKS * MBLKS * 64) return;
    int lane = gid & 63;
    int mblk = (gid >> 6) & 31;
    int kblk = gid >> 11;
    int m  = mblk * 16 + (lane & 15);
    int k0 = kblk * 32 + (lane >> 4) * 8;
    float vals[8];
#pragma unroll
    for (int j = 0; j < 8; ++j){
        int k = k0 + j;
        float p = 0.f;
        if (k < NJK){
            int jj = k / 65;
            int kk = k - jj * 65;
            float a = (kk == 0) ? 1.f : audio[m * 64 + kk - 1];
            float v = (jj == 0) ? 1.f : video[m * 64 + jj - 1];
            p = a * v;
        }
        vals[j] = p;
    }
    uint4 o;
    o.x = pack2(vals[0], vals[1]);
    o.y = pack2(vals[2], vals[3]);
    o.z = pack2(vals[4], vals[5]);
    o.w = pack2(vals[6], vals[7]);
    af[gid] = o;
}

// ---------------- K2: fused Z = VA @ bf16(W1'), depth-2 reg prefetch ----------
// 128x128 tile, BK=64, grid 516 = 4 mt x 129 nt, 4 waves (2x2 of 64x64).
// PF(ks+2) -> named reg set (compile-time parity); compute LDS[ks&1];
// WRITE(ks+1) -> LDS[(ks+1)&1] waits counted vmcnt(36) (PF(ks+2) in flight).
__global__ __launch_bounds__(256, 2) void fusion_gemm(
    const float* __restrict__ W1,
    const uint4* __restrict__ af,
    float* __restrict__ Z)
{
    __shared__ __align__(16) char lds[65536];
    // [0,16K) A buf0 | [16K,32K) A buf1 | [32K,48K) B buf0 | [48K,64K) B buf1

    // bijective XCD swizzle (nwg=516: q=64, r=4)
    int orig = blockIdx.x;
    int xcd  = orig & 7;
    int base = (xcd < 4) ? xcd * 65 : 260 + (xcd - 4) * 64;
    int w    = base + (orig >> 3);
    int nt = w >> 2;          // 0..128
    int mt = w & 3;           // 0..3

    int t    = threadIdx.x;
    int lane = t & 63;
    int wv   = t >> 6;
    int wm   = wv >> 1, wn = wv & 1;

    f32x4 acc[4][4] = {};

    const float* wpanel = W1 + (size_t)nt * (NJK * 128);

    int nb = t & 63;
    int kg = t >> 6;          // wave-uniform

    float vB0[2][2][8], vB1[2][2][8];   // [c][half][j]
    uint4 vA0[4], vA1[4];

#define BLOAD(ks_, vBd)                                                     \
    do {                                                                    \
        if ((ks_) == KSTEPS - 1) {                                          \
            _Pragma("unroll")                                               \
            for (int c = 0; c < 2; ++c){                                    \
                int kr0 = (ks_) * 64 + c * 32 + kg * 8;                     \
                _Pragma("unroll")                                           \
                for (int j = 0; j < 8; ++j){                                \
                    int kr = kr0 + j; kr = kr < 4224 ? kr : 4224;           \
                    vBd[c][0][j] = wpanel[(size_t)kr * 128 + nb];           \
                    vBd[c][1][j] = wpanel[(size_t)kr * 128 + nb + 64];      \
                }                                                           \
            }                                                               \
        } else {                                                            \
            _Pragma("unroll")                                               \
            for (int c = 0; c < 2; ++c){                                    \
                const float* wr = wpanel + (size_t)((ks_) * 64 + c * 32 + kg * 8) * 128 + nb; \
                _Pragma("unroll")                                           \
                for (int j = 0; j < 8; ++j){                                \
                    vBd[c][0][j] = wr[j * 128];                             \
                    vBd[c][1][j] = wr[j * 128 + 64];                        \
                }                                                           \
            }                                                               \
        }                                                                   \
    } while (0)

#define ALOAD(ks_, vAd)                                                     \
    do {                                                                    \
        _Pragma("unroll")                                                   \
        for (int c = 0; c < 4; ++c){                                        \
            int g_ = wv + c * 4;                                            \
            int kblk_ = 2 * (ks_) + (g_ >> 3);                              \
            vAd[c] = af[(size_t)(kblk_ * 32 + mt * 8 + (g_ & 7)) * 64 + lane]; \
        }                                                                   \
    } while (0)

#define WRITE(vBs, vAs, buf_)                                               \
    do {                                                                    \
        char* dsta_ = lds + (buf_) * 16384;                                 \
        _Pragma("unroll")                                                   \
        for (int c = 0; c < 4; ++c)                                         \
            *(uint4*)(dsta_ + (wv + c * 4) * 1024 + lane * 16) = vAs[c];    \
        char* dstb_ = lds + 32768 + (buf_) * 16384;                         \
        _Pragma("unroll")                                                   \
        for (int c = 0; c < 2; ++c){                                        \
            _Pragma("unroll")                                               \
            for (int h = 0; h < 2; ++h){                                    \
                int n_ = nb + h * 64;                                       \
                u32x4 u_;                                                   \
                u_.x = pack2(vBs[c][h][0], vBs[c][h][1]);                   \
                u_.y = pack2(vBs[c][h][2], vBs[c][h][3]);                   \
                u_.z = pack2(vBs[c][h][4], vBs[c][h][5]);                   \
                u_.w = pack2(vBs[c][h][6], vBs[c][h][7]);                   \
                int byte_ = (n_ * 128 + c * 64 + kg * 16) ^ ((n_ & 7) << 4);\
                *(u32x4*)(dstb_ + byte_) = u_;                              \
            }                                                               \
        }                                                                   \
    } while (0)

#define COMPUTE(P)                                                          \
    do {                                                                    \
        const char* sa = lds + (P) * 16384;                                 \
        const char* sb = lds + 32768 + (P) * 16384;                         \
        _Pragma("unroll")                                                   \
        for (int s = 0; s < 2; ++s){                                        \
            bf16x8 a[4], b[4];                                              \
            _Pragma("unroll")                                               \
            for (int f = 0; f < 4; ++f)                                     \
                a[f] = *(const bf16x8*)(sa + (s * 8 + wm * 4 + f) * 1024 + lane * 16); \
            _Pragma("unroll")                                               \
            for (int g = 0; g < 4; ++g){                                    \
                int nr = wn * 64 + g * 16 + (lane & 15);                    \
                int byte = (nr * 128 + s * 64 + (lane >> 4) * 16) ^ ((nr & 7) << 4); \
                b[g] = *(const bf16x8*)(sb + byte);                         \
            }                                                               \
            _Pragma("unroll")                                               \
            for (int f = 0; f < 4; ++f)                                     \
                _Pragma("unroll")                                           \
                for (int g = 0; g < 4; ++g)                                 \
                    acc[f][g] = __builtin_amdgcn_mfma_f32_16x16x32_bf16(a[f], b[g], acc[f][g], 0, 0, 0); \
        }                                                                   \
    } while (0)

    // prologue: PF(0) -> write LDS0 (drains); PF(1) stays in flight
    BLOAD(0, vB0); ALOAD(0, vA0);
    WRITE(vB0, vA0, 0);
    BLOAD(1, vB1); ALOAD(1, vA1);
    __syncthreads();

    for (int ks = 0; ks < KSTEPS; ks += 2){
        // even step (P=0): LDS0 current; PF(ks+2)->set0; WRITE(ks+1)<-set1
        if (ks + 2 < KSTEPS){
            BLOAD(ks + 2, vB0); ALOAD(ks + 2, vA0);
            __builtin_amdgcn_sched_barrier(0);
        }
        COMPUTE(0);
        if (ks + 1 < KSTEPS)
            WRITE(vB1, vA1, 1);          // waits vmcnt(36): PF(ks+2) in flight
        __syncthreads();
        if (ks + 1 >= KSTEPS) break;

        // odd step (P=1): LDS1 current; PF(ks+3)->set1; WRITE(ks+2)<-set0
        if (ks + 3 < KSTEPS){
            BLOAD(ks + 3, vB1); ALOAD(ks + 3, vA1);
            __builtin_amdgcn_sched_barrier(0);
        }
        COMPUTE(1);
        if (ks + 2 < KSTEPS)
            WRITE(vB0, vA0, 0);
        __syncthreads();
    }

    // epilogue: D layout col=lane&15, row=(lane>>4)*4+reg
    int row0 = mt * 128 + wm * 64 + (lane >> 4) * 4;
    int col0 = nt * 128 + wn * 64 + (lane & 15);
#pragma unroll
    for (int f = 0; f < 4; ++f)
#pragma unroll
        for (int g = 0; g < 4; ++g)
#pragma unroll
            for (int r = 0; r < 4; ++r)
                Z[(size_t)(row0 + f * 16 + r) * NTOT + col0 + g * 16] = acc[f][g][r];
}

// ---------------- K3: y1 = relu(b1 + sum_i t1_i * Z[:,i,:]); y2; sigmoid head --
__global__ void tail_mlp(const float* __restrict__ Z,
                         const float* __restrict__ text,
                         const float* __restrict__ b1,
                         const float* __restrict__ W2,
                         const float* __restrict__ b2,
                         const float* __restrict__ W3,
                         const float* __restrict__ b3,
                         float* __restrict__ out)
{
    int b   = blockIdx.x;     // 512
    int tid = threadIdx.x;    // 128
    __shared__ float t1s[NI];
    __shared__ float y1s[POST];
    __shared__ float red[2];

    t1s[tid + 1] = text[b * 128 + tid];
    if (tid == 0) t1s[0] = 1.f;
    __syncthreads();

    const float* zrow = Z + (size_t)b * NTOT;
    float acc = 0.f;
    for (int i = 0; i < NI; ++i)
        acc = fmaf(t1s[i], zrow[i * 128 + tid], acc);
    acc += b1[tid];
    float y1 = fmaxf(acc, 0.f);
    y1s[tid] = y1;
    __syncthreads();

    float a2 = b2[tid];
    for (int q = 0; q < 128; ++q)
        a2 = fmaf(y1s[q], W2[q * 128 + tid], a2);
    float y2 = fmaxf(a2, 0.f);

    float part = y2 * W3[tid];
#pragma unroll
    for (int off = 32; off > 0; off >>= 1)
        part += __shfl_down(part, off);
    if ((tid & 63) == 0) red[tid >> 6] = part;
    __syncthreads();
    if (tid == 0){
        float z = red[0] + red[1] + b3[0];
        out[b] = 6.f / (1.f + expf(-z)) - 3.f;
    }
}

extern "C" void kernel_launch(void* const* d_in, const int* in_sizes, int n_in,
                              void* d_out, int out_size, void* d_ws, size_t ws_size,
                              hipStream_t stream)
{
    const float* audio = (const float*)d_in[0];
    const float* video = (const float*)d_in[1];
    const float* text  = (const float*)d_in[2];
    const float* W1    = (const float*)d_in[3];
    const float* b1    = (const float*)d_in[4];
    const float* W2    = (const float*)d_in[5];
    const float* b2    = (const float*)d_in[6];
    const float* W3    = (const float*)d_in[7];
    const float* b3    = (const float*)d_in[8];
    float* out = (float*)d_out;

    char* ws = (char*)d_ws;
    uint4* af = (uint4*)ws;                       // 4,390,912 B
    float* Z  = (float*)(ws + (8u << 20));        // 33,816,576 B

    int af_granules = KBLKS * MBLKS * 64;         // 274432 threads
    build_af<<<(af_granules + 255) / 256, 256, 0, stream>>>(audio, video, af);
    fusion_gemm<<<516, 256, 0, stream>>>(W1, af, Z);
    tail_mlp<<<512, 128, 0, stream>>>(Z, text, b1, W2, b2, W3, b3, out);
}

// Round 8
// 205.597 us; speedup vs baseline: 5.2331x; 5.2331x over previous
//
#include <hip/hip_runtime.h>
#include <hip/hip_bf16.h>
#include <math.h>

#define POST 128
#define NI 129            // T+1
#define NJK 4225          // 65*65
#define KPAD 4288         // 67*64
#define NTOT 16512        // 129*128
#define KBLKS 134         // KPAD/32 (k-blocks of 32)
#define MBLKS 32          // 512/16
#define KSTEPS 67         // KPAD/64

typedef __attribute__((ext_vector_type(8))) short bf16x8;
typedef __attribute__((ext_vector_type(4))) float f32x4;
typedef __attribute__((ext_vector_type(4))) unsigned int u32x4;

__device__ __forceinline__ unsigned short f2bf(float f){
    unsigned u = __builtin_bit_cast(unsigned, f);
    unsigned r = (u + 0x7FFFu + ((u >> 16) & 1u)) >> 16;   // RNE
    return (unsigned short)r;
}
__device__ __forceinline__ unsigned pack2(float a, float b){
    return (unsigned)f2bf(a) | ((unsigned)f2bf(b) << 16);
}

// ---------------- K1: build VA (bf16) in MFMA A-fragment granule order --------
__global__ void build_af(const float* __restrict__ audio,
                         const float* __restrict__ video,
                         uint4* __restrict__ af)
{
    int gid = blockIdx.x * 256 + threadIdx.x;
    if (gid >= KBLKS * MBLKS * 64) return;
    int lane = gid & 63;
    int mblk = (gid >> 6) & 31;
    int kblk = gid >> 11;
    int m  = mblk * 16 + (lane & 15);
    int k0 = kblk * 32 + (lane >> 4) * 8;
    float vals[8];
#pragma unroll
    for (int j = 0; j < 8; ++j){
        int k = k0 + j;
        float p = 0.f;
        if (k < NJK){
            int jj = k / 65;
            int kk = k - jj * 65;
            float a = (kk == 0) ? 1.f : audio[m * 64 + kk - 1];
            float v = (jj == 0) ? 1.f : video[m * 64 + jj - 1];
            p = a * v;
        }
        vals[j] = p;
    }
    uint4 o;
    o.x = pack2(vals[0], vals[1]);
    o.y = pack2(vals[2], vals[3]);
    o.z = pack2(vals[4], vals[5]);
    o.w = pack2(vals[6], vals[7]);
    af[gid] = o;
}

// ---------------- K2: fused Z = VA @ bf16(W1'), 8-wave depth-1 pipeline -------
// 128x128 tile, BK=64, grid 516 = 4 mt x 129 nt, 8 waves (2m x 4n of 64x32).
// Per-thread staging: 16 fp32 B + 2 uint4 A (light VGPR); LDS dbuf 64KB;
// 2 blocks/CU -> 4 waves/SIMD TLP covers the depth-1 vmcnt stall.
__global__ __launch_bounds__(512, 4) void fusion_gemm(
    const float* __restrict__ W1,
    const uint4* __restrict__ af,
    float* __restrict__ Z)
{
    __shared__ __align__(16) char lds[65536];
    // [0,16K) A buf0 | [16K,32K) A buf1 | [32K,48K) B buf0 | [48K,64K) B buf1

    // bijective XCD swizzle (nwg=516: q=64, r=4)
    int orig = blockIdx.x;
    int xcd  = orig & 7;
    int base = (xcd < 4) ? xcd * 65 : 260 + (xcd - 4) * 64;
    int w    = base + (orig >> 3);
    int nt = w >> 2;          // 0..128
    int mt = w & 3;           // 0..3

    int t    = threadIdx.x;
    int lane = t & 63;
    int wv   = t >> 6;        // 0..7
    int wm   = wv >> 2;       // 0..1  (64 m-rows)
    int wn   = wv & 3;        // 0..3  (32 n-cols)

    f32x4 acc[4][2] = {};

    const float* wpanel = W1 + (size_t)nt * (NJK * 128);

    // B staging: thread covers n = t&127, k rows kq*16 .. kq*16+15
    int n_loc = t & 127;
    int kq    = t >> 7;       // 0..3

    float vB[16];
    uint4 vA[2];

#define BLOAD(ks_)                                                          \
    do {                                                                    \
        if ((ks_) == KSTEPS - 1) {                                          \
            _Pragma("unroll")                                               \
            for (int j = 0; j < 16; ++j){                                   \
                int kr = (ks_) * 64 + kq * 16 + j;                          \
                kr = kr < 4224 ? kr : 4224;   /* tail clamp, A=0 there */   \
                vB[j] = wpanel[(size_t)kr * 128 + n_loc];                   \
            }                                                               \
        } else {                                                            \
            const float* wr = wpanel + (size_t)((ks_) * 64 + kq * 16) * 128 + n_loc; \
            _Pragma("unroll")                                               \
            for (int j = 0; j < 16; ++j)                                    \
                vB[j] = wr[j * 128];                                        \
        }                                                                   \
    } while (0)

#define ALOAD(ks_)                                                          \
    do {                                                                    \
        vA[0] = af[((size_t)(2 * (ks_)    ) * 32 + mt * 8 + wv) * 64 + lane]; \
        vA[1] = af[((size_t)(2 * (ks_) + 1) * 32 + mt * 8 + wv) * 64 + lane]; \
    } while (0)

#define WRITE(buf_)                                                         \
    do {                                                                    \
        char* dsta_ = lds + (buf_) * 16384;                                 \
        *(uint4*)(dsta_ + (     wv) * 1024 + lane * 16) = vA[0];            \
        *(uint4*)(dsta_ + (8  + wv) * 1024 + lane * 16) = vA[1];            \
        char* dstb_ = lds + 32768 + (buf_) * 16384;                         \
        u32x4 u0, u1;                                                       \
        u0.x = pack2(vB[0],  vB[1]);  u0.y = pack2(vB[2],  vB[3]);          \
        u0.z = pack2(vB[4],  vB[5]);  u0.w = pack2(vB[6],  vB[7]);          \
        u1.x = pack2(vB[8],  vB[9]);  u1.y = pack2(vB[10], vB[11]);         \
        u1.z = pack2(vB[12], vB[13]); u1.w = pack2(vB[14], vB[15]);         \
        int b0 = (n_loc * 128 + kq * 32) ^ ((n_loc & 7) << 4);              \
        int b1 = (n_loc * 128 + kq * 32 + 16) ^ ((n_loc & 7) << 4);        \
        *(u32x4*)(dstb_ + b0) = u0;                                         \
        *(u32x4*)(dstb_ + b1) = u1;                                         \
    } while (0)

    // prologue
    BLOAD(0); ALOAD(0);
    WRITE(0);
    __syncthreads();

    for (int ks = 0; ks < KSTEPS; ++ks){
        if (ks + 1 < KSTEPS){
            BLOAD(ks + 1);
            ALOAD(ks + 1);
            __builtin_amdgcn_sched_barrier(0);   // pin: loads issue before compute
        }

        // ---- compute from bufs [ks&1]
        {
            const char* sa = lds + (ks & 1) * 16384;
            const char* sb = lds + 32768 + (ks & 1) * 16384;
#pragma unroll
            for (int s = 0; s < 2; ++s){
                bf16x8 a[4], b[2];
#pragma unroll
                for (int f = 0; f < 4; ++f)
                    a[f] = *(const bf16x8*)(sa + (s * 8 + wm * 4 + f) * 1024 + lane * 16);
#pragma unroll
                for (int g = 0; g < 2; ++g){
                    int nr = wn * 32 + g * 16 + (lane & 15);
                    int byte = (nr * 128 + s * 64 + (lane >> 4) * 16) ^ ((nr & 7) << 4);
                    b[g] = *(const bf16x8*)(sb + byte);
                }
#pragma unroll
                for (int f = 0; f < 4; ++f)
#pragma unroll
                    for (int g = 0; g < 2; ++g)
                        acc[f][g] = __builtin_amdgcn_mfma_f32_16x16x32_bf16(a[f], b[g], acc[f][g], 0, 0, 0);
            }
        }

        if (ks + 1 < KSTEPS)
            WRITE((ks + 1) & 1);
        __syncthreads();
    }

    // epilogue: D layout col=lane&15, row=(lane>>4)*4+reg
    int row0 = mt * 128 + wm * 64 + (lane >> 4) * 4;
    int col0 = nt * 128 + wn * 32 + (lane & 15);
#pragma unroll
    for (int f = 0; f < 4; ++f)
#pragma unroll
        for (int g = 0; g < 2; ++g)
#pragma unroll
            for (int r = 0; r < 4; ++r)
                Z[(size_t)(row0 + f * 16 + r) * NTOT + col0 + g * 16] = acc[f][g][r];
}

// ---------------- K3: y1 = relu(b1 + sum_i t1_i * Z[:,i,:]); y2; sigmoid head --
__global__ void tail_mlp(const float* __restrict__ Z,
                         const float* __restrict__ text,
                         const float* __restrict__ b1,
                         const float* __restrict__ W2,
                         const float* __restrict__ b2,
                         const float* __restrict__ W3,
                         const float* __restrict__ b3,
                         float* __restrict__ out)
{
    int b   = blockIdx.x;     // 512
    int tid = threadIdx.x;    // 128
    __shared__ float t1s[NI];
    __shared__ float y1s[POST];
    __shared__ float red[2];

    t1s[tid + 1] = text[b * 128 + tid];
    if (tid == 0) t1s[0] = 1.f;
    __syncthreads();

    const float* zrow = Z + (size_t)b * NTOT;
    float acc = 0.f;
    for (int i = 0; i < NI; ++i)
        acc = fmaf(t1s[i], zrow[i * 128 + tid], acc);
    acc += b1[tid];
    float y1 = fmaxf(acc, 0.f);
    y1s[tid] = y1;
    __syncthreads();

    float a2 = b2[tid];
    for (int q = 0; q < 128; ++q)
        a2 = fmaf(y1s[q], W2[q * 128 + tid], a2);
    float y2 = fmaxf(a2, 0.f);

    float part = y2 * W3[tid];
#pragma unroll
    for (int off = 32; off > 0; off >>= 1)
        part += __shfl_down(part, off);
    if ((tid & 63) == 0) red[tid >> 6] = part;
    __syncthreads();
    if (tid == 0){
        float z = red[0] + red[1] + b3[0];
        out[b] = 6.f / (1.f + expf(-z)) - 3.f;
    }
}

extern "C" void kernel_launch(void* const* d_in, const int* in_sizes, int n_in,
                              void* d_out, int out_size, void* d_ws, size_t ws_size,
                              hipStream_t stream)
{
    const float* audio = (const float*)d_in[0];
    const float* video = (const float*)d_in[1];
    const float* text  = (const float*)d_in[2];
    const float* W1    = (const float*)d_in[3];
    const float* b1    = (const float*)d_in[4];
    const float* W2    = (const float*)d_in[5];
    const float* b2    = (const float*)d_in[6];
    const float* W3    = (const float*)d_in[7];
    const float* b3    = (const float*)d_in[8];
    float* out = (float*)d_out;

    char* ws = (char*)d_ws;
    uint4* af = (uint4*)ws;                       // 4,390,912 B
    float* Z  = (float*)(ws + (8u << 20));        // 33,816,576 B

    int af_granules = KBLKS * MBLKS * 64;         // 274432 threads
    build_af<<<(af_granules + 255) / 256, 256, 0, stream>>>(audio, video, af);
    fusion_gemm<<<516, 512, 0, stream>>>(W1, af, Z);
    tail_mlp<<<512, 128, 0, stream>>>(Z, text, b1, W2, b2, W3, b3, out);
}

// Round 9
// 199.470 us; speedup vs baseline: 5.3938x; 1.0307x over previous
//
#include <hip/hip_runtime.h>
#include <hip/hip_bf16.h>
#include <math.h>

#define POST 128
#define NI 129            // T+1
#define NJK 4225          // 65*65
#define KPAD 4288         // 67*64
#define NTOT 16512        // 129*128
#define KBLKS 134         // KPAD/32 (k-blocks of 32)
#define MBLKS 32          // 512/16
#define KSTEPS 67         // KPAD/64

typedef __attribute__((ext_vector_type(8))) short bf16x8;
typedef __attribute__((ext_vector_type(4))) float f32x4;
typedef __attribute__((ext_vector_type(4))) unsigned int u32x4;

__device__ __forceinline__ unsigned short f2bf(float f){
    unsigned u = __builtin_bit_cast(unsigned, f);
    unsigned r = (u + 0x7FFFu + ((u >> 16) & 1u)) >> 16;   // RNE
    return (unsigned short)r;
}
__device__ __forceinline__ unsigned pack2(float a, float b){
    return (unsigned)f2bf(a) | ((unsigned)f2bf(b) << 16);
}

// ---------------- K1: build VA (bf16) in MFMA A-fragment granule order --------
__global__ void build_af(const float* __restrict__ audio,
                         const float* __restrict__ video,
                         uint4* __restrict__ af)
{
    int gid = blockIdx.x * 256 + threadIdx.x;
    if (gid >= KBLKS * MBLKS * 64) return;
    int lane = gid & 63;
    int mblk = (gid >> 6) & 31;
    int kblk = gid >> 11;
    int m  = mblk * 16 + (lane & 15);
    int k0 = kblk * 32 + (lane >> 4) * 8;
    float vals[8];
#pragma unroll
    for (int j = 0; j < 8; ++j){
        int k = k0 + j;
        float p = 0.f;
        if (k < NJK){
            int jj = k / 65;
            int kk = k - jj * 65;
            float a = (kk == 0) ? 1.f : audio[m * 64 + kk - 1];
            float v = (jj == 0) ? 1.f : video[m * 64 + jj - 1];
            p = a * v;
        }
        vals[j] = p;
    }
    uint4 o;
    o.x = pack2(vals[0], vals[1]);
    o.y = pack2(vals[2], vals[3]);
    o.z = pack2(vals[4], vals[5]);
    o.w = pack2(vals[6], vals[7]);
    af[gid] = o;
}

// ---------------- K2: fused Z = VA @ bf16(W1'), asm-pinned depth-1 pipeline ---
// 128x128 tile, BK=64, grid 516 = 4 mt x 129 nt, 8 waves (2m x 4n of 64x32).
// Loads = one asm volatile blob (can't be sunk/split); explicit vmcnt(0) +
// sched_barrier before WRITE (rule 18). Layouts identical to R8 (verified).
__global__ __launch_bounds__(512, 4) void fusion_gemm(
    const float* __restrict__ W1,
    const uint4* __restrict__ af,
    float* __restrict__ Z)
{
    __shared__ __align__(16) char lds[65536];
    // [0,16K) A buf0 | [16K,32K) A buf1 | [32K,48K) B buf0 | [48K,64K) B buf1

    // bijective XCD swizzle (nwg=516: q=64, r=4)
    int orig = blockIdx.x;
    int xcd  = orig & 7;
    int base = (xcd < 4) ? xcd * 65 : 260 + (xcd - 4) * 64;
    int w    = base + (orig >> 3);
    int nt = w >> 2;          // 0..128
    int mt = w & 3;           // 0..3

    int t    = threadIdx.x;
    int lane = t & 63;
    int wv   = t >> 6;        // 0..7
    int wm   = wv >> 2;       // 0..1  (64 m-rows)
    int wn   = wv & 3;        // 0..3  (32 n-cols)

    f32x4 acc[4][2] = {};

    const float* wpanel = W1 + (size_t)nt * (NJK * 128);

    // B staging: thread covers n = t&127, k rows kq*16 .. kq*16+15
    int n_loc = t & 127;
    int kq    = t >> 7;       // 0..3

    float vB[16];
    uint4 vA[2];

// asm blob: 16 B-loads (rows kq*16+j, stride 512B) — unsplittable, unsinkable
#define BLOADASM(ks_)                                                       \
    do {                                                                    \
        const float* p0_ = wpanel + (size_t)((ks_) * 64 + kq * 16) * 128 + n_loc; \
        const float* p1_ = p0_ + 1024;                                      \
        asm volatile(                                                       \
            "global_load_dword %0, %16, off\n\t"                            \
            "global_load_dword %1, %16, off offset:512\n\t"                 \
            "global_load_dword %2, %16, off offset:1024\n\t"                \
            "global_load_dword %3, %16, off offset:1536\n\t"                \
            "global_load_dword %4, %16, off offset:2048\n\t"                \
            "global_load_dword %5, %16, off offset:2560\n\t"                \
            "global_load_dword %6, %16, off offset:3072\n\t"                \
            "global_load_dword %7, %16, off offset:3584\n\t"                \
            "global_load_dword %8, %17, off\n\t"                            \
            "global_load_dword %9, %17, off offset:512\n\t"                 \
            "global_load_dword %10, %17, off offset:1024\n\t"               \
            "global_load_dword %11, %17, off offset:1536\n\t"               \
            "global_load_dword %12, %17, off offset:2048\n\t"               \
            "global_load_dword %13, %17, off offset:2560\n\t"               \
            "global_load_dword %14, %17, off offset:3072\n\t"               \
            "global_load_dword %15, %17, off offset:3584"                   \
            : "=&v"(vB[0]), "=&v"(vB[1]), "=&v"(vB[2]), "=&v"(vB[3]),       \
              "=&v"(vB[4]), "=&v"(vB[5]), "=&v"(vB[6]), "=&v"(vB[7]),       \
              "=&v"(vB[8]), "=&v"(vB[9]), "=&v"(vB[10]), "=&v"(vB[11]),     \
              "=&v"(vB[12]), "=&v"(vB[13]), "=&v"(vB[14]), "=&v"(vB[15])    \
            : "v"(p0_), "v"(p1_));                                          \
    } while (0)

// tail variant (ks_ == KSTEPS-1): C loads with row clamp (rows >4224 are x0)
#define BLOADC(ks_)                                                         \
    do {                                                                    \
        _Pragma("unroll")                                                   \
        for (int j = 0; j < 16; ++j){                                       \
            int kr = (ks_) * 64 + kq * 16 + j;                              \
            kr = kr < 4224 ? kr : 4224;                                     \
            vB[j] = wpanel[(size_t)kr * 128 + n_loc];                       \
        }                                                                   \
    } while (0)

#define ALOADASM(ks_)                                                       \
    do {                                                                    \
        const uint4* pa0_ = af + ((size_t)(2 * (ks_)    ) * 32 + mt * 8 + wv) * 64 + lane; \
        const uint4* pa1_ = af + ((size_t)(2 * (ks_) + 1) * 32 + mt * 8 + wv) * 64 + lane; \
        asm volatile(                                                       \
            "global_load_dwordx4 %0, %2, off\n\t"                           \
            "global_load_dwordx4 %1, %3, off"                               \
            : "=&v"(vA[0]), "=&v"(vA[1])                                    \
            : "v"(pa0_), "v"(pa1_));                                        \
    } while (0)

#define WRITE(buf_)                                                         \
    do {                                                                    \
        char* dsta_ = lds + (buf_) * 16384;                                 \
        *(uint4*)(dsta_ + (     wv) * 1024 + lane * 16) = vA[0];            \
        *(uint4*)(dsta_ + (8  + wv) * 1024 + lane * 16) = vA[1];            \
        char* dstb_ = lds + 32768 + (buf_) * 16384;                         \
        u32x4 u0, u1;                                                       \
        u0.x = pack2(vB[0],  vB[1]);  u0.y = pack2(vB[2],  vB[3]);          \
        u0.z = pack2(vB[4],  vB[5]);  u0.w = pack2(vB[6],  vB[7]);          \
        u1.x = pack2(vB[8],  vB[9]);  u1.y = pack2(vB[10], vB[11]);         \
        u1.z = pack2(vB[12], vB[13]); u1.w = pack2(vB[14], vB[15]);         \
        int b0 = (n_loc * 128 + kq * 32) ^ ((n_loc & 7) << 4);              \
        int b1 = (n_loc * 128 + kq * 32 + 16) ^ ((n_loc & 7) << 4);        \
        *(u32x4*)(dstb_ + b0) = u0;                                         \
        *(u32x4*)(dstb_ + b1) = u1;                                         \
    } while (0)

#define VMWAIT()                                                            \
    do {                                                                    \
        asm volatile("s_waitcnt vmcnt(0)" ::: "memory");                    \
        __builtin_amdgcn_sched_barrier(0);                                  \
    } while (0)

    // prologue
    BLOADASM(0); ALOADASM(0);
    VMWAIT();
    WRITE(0);
    __syncthreads();

    for (int ks = 0; ks < KSTEPS; ++ks){
        if (ks + 1 < KSTEPS){
            if (ks + 1 == KSTEPS - 1) BLOADC(ks + 1);
            else                      BLOADASM(ks + 1);
            ALOADASM(ks + 1);
            __builtin_amdgcn_sched_barrier(0);   // loads stay above compute
        }

        // ---- compute from bufs [ks&1]
        {
            const char* sa = lds + (ks & 1) * 16384;
            const char* sb = lds + 32768 + (ks & 1) * 16384;
#pragma unroll
            for (int s = 0; s < 2; ++s){
                bf16x8 a[4], b[2];
#pragma unroll
                for (int f = 0; f < 4; ++f)
                    a[f] = *(const bf16x8*)(sa + (s * 8 + wm * 4 + f) * 1024 + lane * 16);
#pragma unroll
                for (int g = 0; g < 2; ++g){
                    int nr = wn * 32 + g * 16 + (lane & 15);
                    int byte = (nr * 128 + s * 64 + (lane >> 4) * 16) ^ ((nr & 7) << 4);
                    b[g] = *(const bf16x8*)(sb + byte);
                }
#pragma unroll
                for (int f = 0; f < 4; ++f)
#pragma unroll
                    for (int g = 0; g < 2; ++g)
                        acc[f][g] = __builtin_amdgcn_mfma_f32_16x16x32_bf16(a[f], b[g], acc[f][g], 0, 0, 0);
            }
        }

        if (ks + 1 < KSTEPS){
            VMWAIT();                 // asm outputs valid only after this
            WRITE((ks + 1) & 1);
        }
        __syncthreads();
    }

    // epilogue: D layout col=lane&15, row=(lane>>4)*4+reg
    int row0 = mt * 128 + wm * 64 + (lane >> 4) * 4;
    int col0 = nt * 128 + wn * 32 + (lane & 15);
#pragma unroll
    for (int f = 0; f < 4; ++f)
#pragma unroll
        for (int g = 0; g < 2; ++g)
#pragma unroll
            for (int r = 0; r < 4; ++r)
                Z[(size_t)(row0 + f * 16 + r) * NTOT + col0 + g * 16] = acc[f][g][r];
}

// ---------------- K3: y1 = relu(b1 + sum_i t1_i * Z[:,i,:]); y2; sigmoid head --
__global__ void tail_mlp(const float* __restrict__ Z,
                         const float* __restrict__ text,
                         const float* __restrict__ b1,
                         const float* __restrict__ W2,
                         const float* __restrict__ b2,
                         const float* __restrict__ W3,
                         const float* __restrict__ b3,
                         float* __restrict__ out)
{
    int b   = blockIdx.x;     // 512
    int tid = threadIdx.x;    // 128
    __shared__ float t1s[NI];
    __shared__ float y1s[POST];
    __shared__ float red[2];

    t1s[tid + 1] = text[b * 128 + tid];
    if (tid == 0) t1s[0] = 1.f;
    __syncthreads();

    const float* zrow = Z + (size_t)b * NTOT;
    float acc = 0.f;
    for (int i = 0; i < NI; ++i)
        acc = fmaf(t1s[i], zrow[i * 128 + tid], acc);
    acc += b1[tid];
    float y1 = fmaxf(acc, 0.f);
    y1s[tid] = y1;
    __syncthreads();

    float a2 = b2[tid];
    for (int q = 0; q < 128; ++q)
        a2 = fmaf(y1s[q], W2[q * 128 + tid], a2);
    float y2 = fmaxf(a2, 0.f);

    float part = y2 * W3[tid];
#pragma unroll
    for (int off = 32; off > 0; off >>= 1)
        part += __shfl_down(part, off);
    if ((tid & 63) == 0) red[tid >> 6] = part;
    __syncthreads();
    if (tid == 0){
        float z = red[0] + red[1] + b3[0];
        out[b] = 6.f / (1.f + expf(-z)) - 3.f;
    }
}

extern "C" void kernel_launch(void* const* d_in, const int* in_sizes, int n_in,
                              void* d_out, int out_size, void* d_ws, size_t ws_size,
                              hipStream_t stream)
{
    const float* audio = (const float*)d_in[0];
    const float* video = (const float*)d_in[1];
    const float* text  = (const float*)d_in[2];
    const float* W1    = (const float*)d_in[3];
    const float* b1    = (const float*)d_in[4];
    const float* W2    = (const float*)d_in[5];
    const float* b2    = (const float*)d_in[6];
    const float* W3    = (const float*)d_in[7];
    const float* b3    = (const float*)d_in[8];
    float* out = (float*)d_out;

    char* ws = (char*)d_ws;
    uint4* af = (uint4*)ws;                       // 4,390,912 B
    float* Z  = (float*)(ws + (8u << 20));        // 33,816,576 B

    int af_granules = KBLKS * MBLKS * 64;         // 274432 threads
    build_af<<<(af_granules + 255) / 256, 256, 0, stream>>>(audio, video, af);
    fusion_gemm<<<516, 512, 0, stream>>>(W1, af, Z);
    tail_mlp<<<512, 128, 0, stream>>>(Z, text, b1, W2, b2, W3, b3, out);
}